// Round 6
// baseline (398.953 us; speedup 1.0000x reference)
//
#include <hip/hip_runtime.h>

#define NN 50000
#define NE 800000
#define DD 96
#define BN_EPS 1e-5
#define NB 196  // ceil(NN/256)

typedef __attribute__((ext_vector_type(8))) short short8v;
typedef __attribute__((ext_vector_type(4))) float float4v;

__device__ inline float bf2f(unsigned u) { return __uint_as_float(u << 16); }
__device__ inline unsigned short f2bf(float f) {
  unsigned u = __float_as_uint(f);
  return (unsigned short)((u + 0x7FFF + ((u >> 16) & 1)) >> 16);
}
__device__ inline void unpack8(uint4 v, float* f) {
  f[0] = bf2f(v.x & 0xffff); f[1] = bf2f(v.x >> 16);
  f[2] = bf2f(v.y & 0xffff); f[3] = bf2f(v.y >> 16);
  f[4] = bf2f(v.z & 0xffff); f[5] = bf2f(v.z >> 16);
  f[6] = bf2f(v.w & 0xffff); f[7] = bf2f(v.w >> 16);
}
__device__ inline uint4 pack8(const float* f) {
  uint4 v;
  v.x = (unsigned)f2bf(f[0]) | ((unsigned)f2bf(f[1]) << 16);
  v.y = (unsigned)f2bf(f[2]) | ((unsigned)f2bf(f[3]) << 16);
  v.z = (unsigned)f2bf(f[4]) | ((unsigned)f2bf(f[5]) << 16);
  v.w = (unsigned)f2bf(f[6]) | ((unsigned)f2bf(f[7]) << 16);
  return v;
}

// ============ fp32 -> bf16 convert ============
__global__ __launch_bounds__(256) void f2bf_k(const float* __restrict__ in,
                                              unsigned short* __restrict__ out,
                                              int n8) {
  int t = blockIdx.x * 256 + threadIdx.x;
  if (t >= n8) return;
  const float4* p = (const float4*)in + 2 * t;
  float4 a = p[0], b = p[1];
  float f[8] = {a.x, a.y, a.z, a.w, b.x, b.y, b.z, b.w};
  ((uint4*)out)[t] = pack8(f);
}

// ============ CSR build ============
__global__ __launch_bounds__(256) void hist_k(const int* __restrict__ dst,
                                              int* __restrict__ counts) {
  int e = blockIdx.x * 256 + threadIdx.x;
  if (e < NE) atomicAdd(&counts[dst[e]], 1);
}

__global__ __launch_bounds__(256) void scan_part(const int* __restrict__ counts,
                                                 int* __restrict__ bsum) {
  __shared__ int s[256];
  int tid = threadIdx.x;
  int i = blockIdx.x * 256 + tid;
  s[tid] = (i < NN) ? counts[i] : 0;
  __syncthreads();
  for (int st = 128; st > 0; st >>= 1) {
    if (tid < st) s[tid] += s[tid + st];
    __syncthreads();
  }
  if (tid == 0) bsum[blockIdx.x] = s[0];
}

__global__ __launch_bounds__(256) void scan_top(const int* __restrict__ bsum,
                                                int* __restrict__ boff) {
  __shared__ int s[256];
  int tid = threadIdx.x;
  int v = (tid < NB) ? bsum[tid] : 0;
  s[tid] = v;
  __syncthreads();
  for (int off = 1; off < 256; off <<= 1) {
    int t = (tid >= off) ? s[tid - off] : 0;
    __syncthreads();
    s[tid] += t;
    __syncthreads();
  }
  if (tid < NB) boff[tid] = s[tid] - v;
}

__global__ __launch_bounds__(256) void scan_apply(
    const int* __restrict__ counts, const int* __restrict__ boff,
    int* __restrict__ rowstart) {
  __shared__ int s[256];
  int tid = threadIdx.x;
  int i = blockIdx.x * 256 + tid;
  int v = (i < NN) ? counts[i] : 0;
  s[tid] = v;
  __syncthreads();
  for (int off = 1; off < 256; off <<= 1) {
    int t = (tid >= off) ? s[tid - off] : 0;
    __syncthreads();
    s[tid] += t;
    __syncthreads();
  }
  if (i < NN) rowstart[i] = boff[blockIdx.x] + s[tid] - v;
  if (i == 0) rowstart[NN] = NE;
}

// pack entry: low 16 = src node (NN<65536), high 16 = ea as bf16
__global__ __launch_bounds__(256) void scatter_k(
    const int* __restrict__ src, const int* __restrict__ dst,
    const float* __restrict__ ea, const int* __restrict__ rowstart,
    int* __restrict__ cursor, unsigned* __restrict__ pack) {
  int e = blockIdx.x * 256 + threadIdx.x;
  if (e >= NE) return;
  int d = dst[e];
  int p = rowstart[d] + atomicAdd(&cursor[d], 1);
  unsigned v = (unsigned)src[e] | ((unsigned)f2bf(ea[e]) << 16);
  __builtin_nontemporal_store(v, &pack[p]);
}

// ===== wave-per-node CSR aggregation: lane = (c8, es), 5 edges in flight =====
__global__ __launch_bounds__(256) void agg_wave(
    const unsigned short* __restrict__ xin, const float* __restrict__ lw,
    const float* __restrict__ lb, const int* __restrict__ rowstart,
    const unsigned* __restrict__ pack, unsigned short* __restrict__ out) {
  int n = blockIdx.x * 4 + (threadIdx.x >> 6);  // grid exactly NN/4
  int lane = threadIdx.x & 63;
  int es = lane / 12;       // 0..5 (es==5 idle)
  int c8 = lane - es * 12;  // 0..11
  float lwv[8], lbv[8], acc[8];
#pragma unroll
  for (int i = 0; i < 8; i++) {
    lwv[i] = lw[c8 * 8 + i];
    lbv[i] = lb[c8 * 8 + i];
    acc[i] = 0.f;
  }
  if (es == 0) {
    uint4 xo = *(const uint4*)(xin + (size_t)n * DD + c8 * 8);
    unpack8(xo, acc);
  }
  int beg = rowstart[n], end = rowstart[n + 1];
  if (lane < 60) {
    for (int i = beg + es; i < end; i += 5) {
      unsigned pk = pack[i];
      int s = pk & 0xffff;
      float ev = bf2f(pk >> 16);
      uint4 xv = *(const uint4*)(xin + (size_t)s * DD + c8 * 8);
      float xs[8];
      unpack8(xv, xs);
#pragma unroll
      for (int j = 0; j < 8; j++)
        acc[j] += fmaxf(xs[j] + fmaf(ev, lwv[j], lbv[j]), 0.0f);
    }
  }
#pragma unroll
  for (int j = 0; j < 8; j++) {
    float a = acc[j];
    float t1 = __shfl_down(a, 12);
    float t2 = __shfl_down(a, 24);
    float t3 = __shfl_down(a, 36);
    float t4 = __shfl_down(a, 48);
    acc[j] = a + t1 + t2 + t3 + t4;
  }
  if (es == 0)
    *(uint4*)(out + (size_t)n * DD + c8 * 8) = pack8(acc);
}

// ===== same, with BN affine applied on the fly =====
__global__ __launch_bounds__(256) void agg_wave_norm(
    const unsigned short* __restrict__ h, const float* __restrict__ coeff,
    const float* __restrict__ lw, const float* __restrict__ lb,
    const int* __restrict__ rowstart, const unsigned* __restrict__ pack,
    unsigned short* __restrict__ out) {
  int n = blockIdx.x * 4 + (threadIdx.x >> 6);
  int lane = threadIdx.x & 63;
  int es = lane / 12;
  int c8 = lane - es * 12;
  float sc[8], tsh[8], tlb[8], lwv[8], acc[8];
#pragma unroll
  for (int i = 0; i < 8; i++) {
    sc[i] = coeff[c8 * 8 + i];
    tsh[i] = coeff[96 + c8 * 8 + i];
    tlb[i] = tsh[i] + lb[c8 * 8 + i];
    lwv[i] = lw[c8 * 8 + i];
    acc[i] = 0.f;
  }
  if (es == 0) {
    uint4 xo = *(const uint4*)(h + (size_t)n * DD + c8 * 8);
    float f[8];
    unpack8(xo, f);
#pragma unroll
    for (int i = 0; i < 8; i++) acc[i] = fmaf(sc[i], f[i], tsh[i]);
  }
  int beg = rowstart[n], end = rowstart[n + 1];
  if (lane < 60) {
    for (int i = beg + es; i < end; i += 5) {
      unsigned pk = pack[i];
      int s = pk & 0xffff;
      float ev = bf2f(pk >> 16);
      uint4 xv = *(const uint4*)(h + (size_t)s * DD + c8 * 8);
      float xs[8];
      unpack8(xv, xs);
#pragma unroll
      for (int j = 0; j < 8; j++) {
        float base = fmaf(ev, lwv[j], tlb[j]);
        acc[j] += fmaxf(fmaf(sc[j], xs[j], base), 0.0f);
      }
    }
  }
#pragma unroll
  for (int j = 0; j < 8; j++) {
    float a = acc[j];
    float t1 = __shfl_down(a, 12);
    float t2 = __shfl_down(a, 24);
    float t3 = __shfl_down(a, 36);
    float t4 = __shfl_down(a, 48);
    acc[j] = a + t1 + t2 + t3 + t4;
  }
  if (es == 0)
    *(uint4*)(out + (size_t)n * DD + c8 * 8) = pack8(acc);
}

// ============ W prep: fold BN scales (two regions), bf16, swizzle ========
template <int K, int M, int KA, int KB>
__global__ __launch_bounds__(256) void wprep(const float* __restrict__ W,
                                             const float* __restrict__ b,
                                             const float* __restrict__ cA,
                                             const float* __restrict__ cB,
                                             unsigned short* __restrict__ Wz,
                                             float* __restrict__ bf) {
  constexpr int KT = K / 32, MT = M / 16;
  int t = blockIdx.x * 256 + threadIdx.x;
  if (t < KT * MT * 64) {
    int lane = t & 63, fr = t >> 6;
    int kt = fr / MT, ct = fr - kt * MT;
    int col = ct * 16 + (lane & 15);
    int k0 = kt * 32 + (lane >> 4) * 8;
    float f[8];
#pragma unroll
    for (int j = 0; j < 8; j++) {
      int k = k0 + j;
      float w = W[k * M + col];
      if (KA > 0 && k < KA) w *= cA[k];
      if (KB > 0 && k >= KA && k < KA + KB) w *= cB[k - KA];
      f[j] = w;
    }
    ((uint4*)Wz)[t] = pack8(f);
  } else if (t < KT * MT * 64 + M) {
    int j = t - KT * MT * 64;
    float acc = b[j];
    if (KA > 0)
      for (int k = 0; k < KA; k++) acc += cA[KA + k] * W[k * M + j];
    if (KB > 0)
      for (int k = 0; k < KB; k++) acc += cB[KB + k] * W[(KA + k) * M + j];
    bf[j] = acc;
  }
}

// ============ MFMA GEMM + bias + relu + column stats ============
template <int K1, int K2, int M, bool OUTF32>
__global__ __launch_bounds__(256) void gemm_mfma(
    const unsigned short* __restrict__ A1,
    const unsigned short* __restrict__ A2,
    const unsigned short* __restrict__ Wz, const float* __restrict__ bias,
    void* __restrict__ hOut, double* __restrict__ stats) {
  constexpr int K = K1 + K2;
  constexpr int KT = K / 32;
  constexpr int MT = M / 16;
  constexpr int NT = NN / 16;  // 3125
  int tid = threadIdx.x;
  int wave = tid >> 6, lane = tid & 63;
  int lr = lane & 15, lk = lane >> 4;

  float bj[MT], s[MT], q[MT];
#pragma unroll
  for (int ct = 0; ct < MT; ct++) {
    bj[ct] = bias[ct * 16 + lr];
    s[ct] = 0.f;
    q[ct] = 0.f;
  }

  for (int tt = blockIdx.x * 4 + wave; tt < NT; tt += gridDim.x * 4) {
    float4v acc[MT];
#pragma unroll
    for (int ct = 0; ct < MT; ct++) acc[ct] = (float4v){0.f, 0.f, 0.f, 0.f};

    const unsigned short* a1 = A1 + (size_t)(tt * 16 + lr) * K1 + lk * 8;
    const unsigned short* a2 =
        (K2 > 0) ? A2 + (size_t)(tt * 16 + lr) * K2 + lk * 8 : a1;
#pragma unroll
    for (int kt = 0; kt < KT; kt++) {
      short8v av;
      if (kt * 32 < K1)
        av = *reinterpret_cast<const short8v*>(a1 + kt * 32);
      else
        av = *reinterpret_cast<const short8v*>(a2 + (kt * 32 - K1));
#pragma unroll
      for (int ct = 0; ct < MT; ct++) {
        short8v bv = *reinterpret_cast<const short8v*>(
            Wz + ((size_t)(kt * MT + ct) * 64 + lane) * 8);
        acc[ct] =
            __builtin_amdgcn_mfma_f32_16x16x32_bf16(av, bv, acc[ct], 0, 0, 0);
      }
    }
#pragma unroll
    for (int ct = 0; ct < MT; ct++) {
#pragma unroll
      for (int i = 0; i < 4; i++) {
        float o = fmaxf(acc[ct][i] + bj[ct], 0.f);
        size_t row = (size_t)tt * 16 + lk * 4 + i;
        if (OUTF32)
          ((float*)hOut)[row * M + ct * 16 + lr] = o;
        else
          ((unsigned short*)hOut)[row * M + ct * 16 + lr] = f2bf(o);
        s[ct] += o;
        q[ct] += o * o;
      }
    }
  }

  __shared__ float sred[4][M], qred[4][M];
#pragma unroll
  for (int ct = 0; ct < MT; ct++) {
    float ss = s[ct], qq = q[ct];
    ss += __shfl_xor(ss, 16);
    ss += __shfl_xor(ss, 32);
    qq += __shfl_xor(qq, 16);
    qq += __shfl_xor(qq, 32);
    if (lk == 0) {
      sred[wave][ct * 16 + lr] = ss;
      qred[wave][ct * 16 + lr] = qq;
    }
  }
  __syncthreads();
  if (tid < M) {
    double ss = (double)sred[0][tid] + sred[1][tid] + sred[2][tid] + sred[3][tid];
    double qq = (double)qred[0][tid] + qred[1][tid] + qred[2][tid] + qred[3][tid];
    atomicAdd(&stats[tid], ss);
    atomicAdd(&stats[M + tid], qq);
  }
}

// ============ BN coeffs ============
template <int M>
__global__ void bn_coeffs(const double* __restrict__ stats,
                          const float* __restrict__ g,
                          const float* __restrict__ beta,
                          float* __restrict__ coeff) {
  int j = threadIdx.x;
  if (j >= M) return;
  double mu = stats[j] / (double)NN;
  double var = stats[M + j] / (double)NN - mu * mu;
  double inv = 1.0 / sqrt(var + (double)BN_EPS);
  double scale = (double)g[j] * inv;
  coeff[j] = (float)scale;
  coeff[M + j] = (float)((double)beta[j] - mu * scale);
}

// ============ final: BN coeffs + normalize, M=16, fp32 ============
__global__ __launch_bounds__(256) void bnout(const float4* __restrict__ h,
                                             const double* __restrict__ stats,
                                             const float* __restrict__ g,
                                             const float* __restrict__ beta,
                                             float4* __restrict__ out) {
  __shared__ float sc[16], sh[16];
  int tid = threadIdx.x;
  if (tid < 16) {
    double mu = stats[tid] / (double)NN;
    double var = stats[16 + tid] / (double)NN - mu * mu;
    double inv = 1.0 / sqrt(var + (double)BN_EPS);
    double scale = (double)g[tid] * inv;
    sc[tid] = (float)scale;
    sh[tid] = (float)((double)beta[tid] - mu * scale);
  }
  __syncthreads();
  int t = blockIdx.x * 256 + tid;
  if (t >= NN * 4) return;
  float4 v = h[t];
  int j0 = (4 * t) & 15;
  float4 o;
  o.x = fmaf(v.x, sc[j0 + 0], sh[j0 + 0]);
  o.y = fmaf(v.y, sc[j0 + 1], sh[j0 + 1]);
  o.z = fmaf(v.z, sc[j0 + 2], sh[j0 + 2]);
  o.w = fmaf(v.w, sc[j0 + 3], sh[j0 + 3]);
  out[t] = o;
}

static inline char* alignup(char* p, size_t a) {
  return (char*)(((uintptr_t)p + a - 1) & ~(uintptr_t)(a - 1));
}

extern "C" void kernel_launch(void* const* d_in, const int* in_sizes, int n_in,
                              void* d_out, int out_size, void* d_ws,
                              size_t ws_size, hipStream_t stream) {
  const float* x = (const float*)d_in[0];
  const float* ea = (const float*)d_in[1];
  const int* ei = (const int*)d_in[2];
  const int* src = ei;
  const int* dst = ei + NE;
  const float* lin_w = (const float*)d_in[3];
  const float* lin_b = (const float*)d_in[4];
  const float* c1_w = (const float*)d_in[5];
  const float* c1_b = (const float*)d_in[6];
  const float* c1_g = (const float*)d_in[7];
  const float* c1_be = (const float*)d_in[8];
  const float* c2_w = (const float*)d_in[9];
  const float* c2_b = (const float*)d_in[10];
  const float* c2_g = (const float*)d_in[11];
  const float* c2_be = (const float*)d_in[12];
  const float* l1_w = (const float*)d_in[13];
  const float* l1_b = (const float*)d_in[14];
  const float* l1_g = (const float*)d_in[15];
  const float* l1_be = (const float*)d_in[16];
  const float* ma_w = (const float*)d_in[17];
  const float* ma_b = (const float*)d_in[18];
  const float* ma_g = (const float*)d_in[19];
  const float* ma_be = (const float*)d_in[20];
  const float* mb_w = (const float*)d_in[21];
  const float* mb_b = (const float*)d_in[22];
  const float* mb_g = (const float*)d_in[23];
  const float* mb_be = (const float*)d_in[24];

  typedef unsigned short us;
  char* p = (char*)d_ws;
  us* xb = (us*)p;   p += (size_t)NN * 96 * 2;
  us* Ab = (us*)p;   p += (size_t)NN * 96 * 2;
  us* H1 = (us*)p;   p += (size_t)NN * 96 * 2;
  us* H2 = (us*)p;   p += (size_t)NN * 64 * 2;
  us* H3 = (us*)p;   p += (size_t)NN * 96 * 2;
  us* H4 = (us*)p;   p += (size_t)NN * 96 * 2;
  float* H5 = (float*)p; p += (size_t)NN * 16 * 4;
  p = alignup(p, 256);
  us* Wz1 = (us*)p;  p += 3 * 6 * 64 * 8 * 2;
  us* Wz2 = (us*)p;  p += 3 * 4 * 64 * 8 * 2;
  us* Wz3 = (us*)p;  p += 5 * 6 * 64 * 8 * 2;
  us* Wz4 = (us*)p;  p += 3 * 6 * 64 * 8 * 2;
  us* Wz5 = (us*)p;  p += 3 * 1 * 64 * 8 * 2;
  p = alignup(p, 256);
  float* bf1 = (float*)p; p += 96 * 4;
  float* bf2 = (float*)p; p += 64 * 4;
  float* bf3 = (float*)p; p += 96 * 4;
  float* bf4 = (float*)p; p += 96 * 4;
  float* bf5 = (float*)p; p += 16 * 4;
  float* coeffs = (float*)p; p += 4 * 192 * 4;
  p = alignup(p, 256);
  char* zbase = p;
  int* counts = (int*)p;  p += (size_t)NN * 4;
  int* cursor = (int*)p;  p += (size_t)NN * 4;
  double* stats = (double*)p; p += (size_t)5 * 192 * 8;
  size_t zbytes = (size_t)(p - zbase);
  int* rowstart = (int*)p; p += (size_t)(NN + 1) * 4;
  int* bsum = (int*)p;    p += 256 * 4;
  int* boff = (int*)p;    p += 256 * 4;
  p = alignup(p, 8);
  unsigned* pack = (unsigned*)p; p += (size_t)NE * 4;

  float* c1 = coeffs;
  float* c2 = coeffs + 192;
  float* c3 = coeffs + 384;
  float* c4 = coeffs + 576;

  hipMemsetAsync(zbase, 0, zbytes, stream);

  const int eb = (NE + 255) / 256;
  const int n12 = NN * 12;
  const int b12 = (n12 + 255) / 256;
  const int aggG = NN / 4;  // 12500, exact
  const int GG = 512;

  // ---- prep ----
  f2bf_k<<<b12, 256, 0, stream>>>(x, xb, n12);
  hist_k<<<eb, 256, 0, stream>>>(dst, counts);
  scan_part<<<NB, 256, 0, stream>>>(counts, bsum);
  scan_top<<<1, 256, 0, stream>>>(bsum, boff);
  scan_apply<<<NB, 256, 0, stream>>>(counts, boff, rowstart);
  scatter_k<<<eb, 256, 0, stream>>>(src, dst, ea, rowstart, cursor, pack);

  // ---- conv1 ----
  agg_wave<<<aggG, 256, 0, stream>>>(xb, lin_w, lin_b, rowstart, pack, Ab);
  wprep<96, 96, 0, 0><<<5, 256, 0, stream>>>(c1_w, c1_b, nullptr, nullptr, Wz1,
                                             bf1);
  gemm_mfma<96, 0, 96, false><<<GG, 256, 0, stream>>>(Ab, nullptr, Wz1, bf1,
                                                      H1, stats);
  bn_coeffs<96><<<1, 96, 0, stream>>>(stats, c1_g, c1_be, c1);

  // ---- conv2 (BN1 applied on the fly to H1) ----
  agg_wave_norm<<<aggG, 256, 0, stream>>>(H1, c1, lin_w, lin_b, rowstart, pack,
                                          Ab);
  wprep<96, 64, 0, 0><<<4, 256, 0, stream>>>(c2_w, c2_b, nullptr, nullptr, Wz2,
                                             bf2);
  gemm_mfma<96, 0, 64, false><<<GG, 256, 0, stream>>>(Ab, nullptr, Wz2, bf2,
                                                      H2, stats + 192);
  bn_coeffs<64><<<1, 64, 0, stream>>>(stats + 192, c2_g, c2_be, c2);

  // ---- lin1 on concat([H1(BN1 folded), H2(BN2 folded)]) ----
  wprep<160, 96, 96, 64><<<8, 256, 0, stream>>>(l1_w, l1_b, c1, c2, Wz3, bf3);
  gemm_mfma<96, 64, 96, false><<<GG, 256, 0, stream>>>(H1, H2, Wz3, bf3, H3,
                                                       stats + 384);
  bn_coeffs<96><<<1, 96, 0, stream>>>(stats + 384, l1_g, l1_be, c3);

  // ---- mlp1a (BN3 folded) ----
  wprep<96, 96, 96, 0><<<5, 256, 0, stream>>>(ma_w, ma_b, c3, nullptr, Wz4,
                                              bf4);
  gemm_mfma<96, 0, 96, false><<<GG, 256, 0, stream>>>(H3, nullptr, Wz4, bf4,
                                                      H4, stats + 576);
  bn_coeffs<96><<<1, 96, 0, stream>>>(stats + 576, ma_g, ma_be, c4);

  // ---- mlp1b (BN4 folded) -> H5 fp32, then fused BN5+write ----
  wprep<96, 16, 96, 0><<<1, 256, 0, stream>>>(mb_w, mb_b, c4, nullptr, Wz5,
                                              bf5);
  gemm_mfma<96, 0, 16, true><<<GG, 256, 0, stream>>>(H4, nullptr, Wz5, bf5, H5,
                                                     stats + 768);
  bnout<<<(NN * 4 + 255) / 256, 256, 0, stream>>>(
      (const float4*)H5, stats + 768, mb_g, mb_be, (float4*)d_out);
}

// Round 7
// 369.734 us; speedup vs baseline: 1.0790x; 1.0790x over previous
//
#include <hip/hip_runtime.h>

#define NN 50000
#define NE 800000
#define DD 96
#define BN_EPS 1e-5
#define NB 196  // ceil(NN/256)

typedef __attribute__((ext_vector_type(8))) short short8v;
typedef __attribute__((ext_vector_type(4))) float float4v;

__device__ inline float bf2f(unsigned u) { return __uint_as_float(u << 16); }
__device__ inline unsigned short f2bf(float f) {
  unsigned u = __float_as_uint(f);
  return (unsigned short)((u + 0x7FFF + ((u >> 16) & 1)) >> 16);
}
__device__ inline void unpack8(uint4 v, float* f) {
  f[0] = bf2f(v.x & 0xffff); f[1] = bf2f(v.x >> 16);
  f[2] = bf2f(v.y & 0xffff); f[3] = bf2f(v.y >> 16);
  f[4] = bf2f(v.z & 0xffff); f[5] = bf2f(v.z >> 16);
  f[6] = bf2f(v.w & 0xffff); f[7] = bf2f(v.w >> 16);
}
__device__ inline uint4 pack8(const float* f) {
  uint4 v;
  v.x = (unsigned)f2bf(f[0]) | ((unsigned)f2bf(f[1]) << 16);
  v.y = (unsigned)f2bf(f[2]) | ((unsigned)f2bf(f[3]) << 16);
  v.z = (unsigned)f2bf(f[4]) | ((unsigned)f2bf(f[5]) << 16);
  v.w = (unsigned)f2bf(f[6]) | ((unsigned)f2bf(f[7]) << 16);
  return v;
}

// ============ fp32 -> bf16 convert ============
__global__ __launch_bounds__(256) void f2bf_k(const float* __restrict__ in,
                                              unsigned short* __restrict__ out,
                                              int n8) {
  int t = blockIdx.x * 256 + threadIdx.x;
  if (t >= n8) return;
  const float4* p = (const float4*)in + 2 * t;
  float4 a = p[0], b = p[1];
  float f[8] = {a.x, a.y, a.z, a.w, b.x, b.y, b.z, b.w};
  ((uint4*)out)[t] = pack8(f);
}

// ============ CSR build: histogram + per-edge rank in one pass ============
__global__ __launch_bounds__(256) void hist_rank(const int* __restrict__ dst,
                                                 int* __restrict__ counts,
                                                 int* __restrict__ rank) {
  int e = blockIdx.x * 256 + threadIdx.x;
  if (e < NE) rank[e] = atomicAdd(&counts[dst[e]], 1);
}

__global__ __launch_bounds__(256) void scan_part(const int* __restrict__ counts,
                                                 int* __restrict__ bsum) {
  __shared__ int s[256];
  int tid = threadIdx.x;
  int i = blockIdx.x * 256 + tid;
  s[tid] = (i < NN) ? counts[i] : 0;
  __syncthreads();
  for (int st = 128; st > 0; st >>= 1) {
    if (tid < st) s[tid] += s[tid + st];
    __syncthreads();
  }
  if (tid == 0) bsum[blockIdx.x] = s[0];
}

__global__ __launch_bounds__(256) void scan_top(const int* __restrict__ bsum,
                                                int* __restrict__ boff) {
  __shared__ int s[256];
  int tid = threadIdx.x;
  int v = (tid < NB) ? bsum[tid] : 0;
  s[tid] = v;
  __syncthreads();
  for (int off = 1; off < 256; off <<= 1) {
    int t = (tid >= off) ? s[tid - off] : 0;
    __syncthreads();
    s[tid] += t;
    __syncthreads();
  }
  if (tid < NB) boff[tid] = s[tid] - v;
}

__global__ __launch_bounds__(256) void scan_apply(
    const int* __restrict__ counts, const int* __restrict__ boff,
    int* __restrict__ rowstart) {
  __shared__ int s[256];
  int tid = threadIdx.x;
  int i = blockIdx.x * 256 + tid;
  int v = (i < NN) ? counts[i] : 0;
  s[tid] = v;
  __syncthreads();
  for (int off = 1; off < 256; off <<= 1) {
    int t = (tid >= off) ? s[tid - off] : 0;
    __syncthreads();
    s[tid] += t;
    __syncthreads();
  }
  if (i < NN) rowstart[i] = boff[blockIdx.x] + s[tid] - v;
  if (i == 0) rowstart[NN] = NE;
}

// pack entry: low 16 = src node (NN<65536), high 16 = ea as bf16
// no atomics here (rank precomputed); plain store so L2 merges lines
__global__ __launch_bounds__(256) void scatter_k(
    const int* __restrict__ src, const int* __restrict__ dst,
    const float* __restrict__ ea, const int* __restrict__ rowstart,
    const int* __restrict__ rank, unsigned* __restrict__ pack) {
  int e = blockIdx.x * 256 + threadIdx.x;
  if (e >= NE) return;
  int p = rowstart[dst[e]] + rank[e];
  pack[p] = (unsigned)src[e] | ((unsigned)f2bf(ea[e]) << 16);
}

// ===== wave-per-node CSR aggregation: lane = (c8, es), 2x5 edges in flight ===
__global__ __launch_bounds__(256) void agg_wave(
    const unsigned short* __restrict__ xin, const float* __restrict__ lw,
    const float* __restrict__ lb, const int* __restrict__ rowstart,
    const unsigned* __restrict__ pack, unsigned short* __restrict__ out) {
  int n = blockIdx.x * 4 + (threadIdx.x >> 6);  // grid exactly NN/4
  int lane = threadIdx.x & 63;
  int es = lane / 12;       // 0..5 (es==5 idle)
  int c8 = lane - es * 12;  // 0..11
  float lwv[8], lbv[8], acc[8];
#pragma unroll
  for (int i = 0; i < 8; i++) {
    lwv[i] = lw[c8 * 8 + i];
    lbv[i] = lb[c8 * 8 + i];
    acc[i] = 0.f;
  }
  if (es == 0) {
    uint4 xo = *(const uint4*)(xin + (size_t)n * DD + c8 * 8);
    unpack8(xo, acc);
  }
  int beg = rowstart[n], end = rowstart[n + 1];
  if (lane < 60) {
    int i = beg + es;
    for (; i + 5 < end; i += 10) {
      unsigned pk0 = pack[i], pk1 = pack[i + 5];
      float ev0 = bf2f(pk0 >> 16), ev1 = bf2f(pk1 >> 16);
      uint4 xv0 = *(const uint4*)(xin + (size_t)(pk0 & 0xffff) * DD + c8 * 8);
      uint4 xv1 = *(const uint4*)(xin + (size_t)(pk1 & 0xffff) * DD + c8 * 8);
      float xs0[8], xs1[8];
      unpack8(xv0, xs0);
      unpack8(xv1, xs1);
#pragma unroll
      for (int j = 0; j < 8; j++) {
        acc[j] += fmaxf(xs0[j] + fmaf(ev0, lwv[j], lbv[j]), 0.0f);
        acc[j] += fmaxf(xs1[j] + fmaf(ev1, lwv[j], lbv[j]), 0.0f);
      }
    }
    if (i < end) {
      unsigned pk = pack[i];
      float ev = bf2f(pk >> 16);
      uint4 xv = *(const uint4*)(xin + (size_t)(pk & 0xffff) * DD + c8 * 8);
      float xs[8];
      unpack8(xv, xs);
#pragma unroll
      for (int j = 0; j < 8; j++)
        acc[j] += fmaxf(xs[j] + fmaf(ev, lwv[j], lbv[j]), 0.0f);
    }
  }
#pragma unroll
  for (int j = 0; j < 8; j++) {
    float a = acc[j];
    float t1 = __shfl_down(a, 12);
    float t2 = __shfl_down(a, 24);
    float t3 = __shfl_down(a, 36);
    float t4 = __shfl_down(a, 48);
    acc[j] = a + t1 + t2 + t3 + t4;
  }
  if (es == 0)
    *(uint4*)(out + (size_t)n * DD + c8 * 8) = pack8(acc);
}

// ===== same, with BN affine computed in-block from stats and applied =====
__global__ __launch_bounds__(256) void agg_wave_norm(
    const unsigned short* __restrict__ h, const double* __restrict__ st,
    const float* __restrict__ g, const float* __restrict__ be,
    const float* __restrict__ lw, const float* __restrict__ lb,
    const int* __restrict__ rowstart, const unsigned* __restrict__ pack,
    unsigned short* __restrict__ out) {
  __shared__ float scs[96], shs[96];
  int tid = threadIdx.x;
  if (tid < 96) {
    double mu = st[tid] / (double)NN;
    double var = st[96 + tid] / (double)NN - mu * mu;
    double inv = 1.0 / sqrt(var + (double)BN_EPS);
    double sc = (double)g[tid] * inv;
    scs[tid] = (float)sc;
    shs[tid] = (float)((double)be[tid] - mu * sc);
  }
  __syncthreads();
  int n = blockIdx.x * 4 + (tid >> 6);
  int lane = tid & 63;
  int es = lane / 12;
  int c8 = lane - es * 12;
  float sc[8], tsh[8], tlb[8], lwv[8], acc[8];
#pragma unroll
  for (int i = 0; i < 8; i++) {
    sc[i] = scs[c8 * 8 + i];
    tsh[i] = shs[c8 * 8 + i];
    tlb[i] = tsh[i] + lb[c8 * 8 + i];
    lwv[i] = lw[c8 * 8 + i];
    acc[i] = 0.f;
  }
  if (es == 0) {
    uint4 xo = *(const uint4*)(h + (size_t)n * DD + c8 * 8);
    float f[8];
    unpack8(xo, f);
#pragma unroll
    for (int i = 0; i < 8; i++) acc[i] = fmaf(sc[i], f[i], tsh[i]);
  }
  int beg = rowstart[n], end = rowstart[n + 1];
  if (lane < 60) {
    int i = beg + es;
    for (; i + 5 < end; i += 10) {
      unsigned pk0 = pack[i], pk1 = pack[i + 5];
      float ev0 = bf2f(pk0 >> 16), ev1 = bf2f(pk1 >> 16);
      uint4 xv0 = *(const uint4*)(h + (size_t)(pk0 & 0xffff) * DD + c8 * 8);
      uint4 xv1 = *(const uint4*)(h + (size_t)(pk1 & 0xffff) * DD + c8 * 8);
      float xs0[8], xs1[8];
      unpack8(xv0, xs0);
      unpack8(xv1, xs1);
#pragma unroll
      for (int j = 0; j < 8; j++) {
        acc[j] += fmaxf(fmaf(sc[j], xs0[j], fmaf(ev0, lwv[j], tlb[j])), 0.0f);
        acc[j] += fmaxf(fmaf(sc[j], xs1[j], fmaf(ev1, lwv[j], tlb[j])), 0.0f);
      }
    }
    if (i < end) {
      unsigned pk = pack[i];
      float ev = bf2f(pk >> 16);
      uint4 xv = *(const uint4*)(h + (size_t)(pk & 0xffff) * DD + c8 * 8);
      float xs[8];
      unpack8(xv, xs);
#pragma unroll
      for (int j = 0; j < 8; j++)
        acc[j] += fmaxf(fmaf(sc[j], xs[j], fmaf(ev, lwv[j], tlb[j])), 0.0f);
    }
  }
#pragma unroll
  for (int j = 0; j < 8; j++) {
    float a = acc[j];
    float t1 = __shfl_down(a, 12);
    float t2 = __shfl_down(a, 24);
    float t3 = __shfl_down(a, 36);
    float t4 = __shfl_down(a, 48);
    acc[j] = a + t1 + t2 + t3 + t4;
  }
  if (es == 0)
    *(uint4*)(out + (size_t)n * DD + c8 * 8) = pack8(acc);
}

// ============ W prep: BN coeffs from stats (in-LDS), fold, bf16, swizzle =====
// Region A rows [0,KA) scaled by BN(statsA,gA,beA); region B rows [KA,KA+KB).
template <int K, int M, int KA, int KB>
__global__ __launch_bounds__(256) void wprep(
    const float* __restrict__ W, const float* __restrict__ b,
    const double* __restrict__ stA, const float* __restrict__ gA,
    const float* __restrict__ beA, const double* __restrict__ stB,
    const float* __restrict__ gB, const float* __restrict__ beB,
    unsigned short* __restrict__ Wz, float* __restrict__ bf) {
  constexpr int KT = K / 32, MT = M / 16;
  __shared__ float scA[KA > 0 ? KA : 1], shA[KA > 0 ? KA : 1];
  __shared__ float scB[KB > 0 ? KB : 1], shB[KB > 0 ? KB : 1];
  int tid = threadIdx.x;
  if (KA > 0 && tid < KA) {
    double mu = stA[tid] / (double)NN;
    double var = stA[KA + tid] / (double)NN - mu * mu;
    double inv = 1.0 / sqrt(var + (double)BN_EPS);
    double sc = (double)gA[tid] * inv;
    scA[tid] = (float)sc;
    shA[tid] = (float)((double)beA[tid] - mu * sc);
  }
  if (KB > 0 && tid < KB) {
    double mu = stB[tid] / (double)NN;
    double var = stB[KB + tid] / (double)NN - mu * mu;
    double inv = 1.0 / sqrt(var + (double)BN_EPS);
    double sc = (double)gB[tid] * inv;
    scB[tid] = (float)sc;
    shB[tid] = (float)((double)beB[tid] - mu * sc);
  }
  if (KA > 0 || KB > 0) __syncthreads();

  int t = blockIdx.x * 256 + tid;
  if (t < KT * MT * 64) {
    int lane = t & 63, fr = t >> 6;
    int kt = fr / MT, ct = fr - kt * MT;
    int col = ct * 16 + (lane & 15);
    int k0 = kt * 32 + (lane >> 4) * 8;
    float f[8];
#pragma unroll
    for (int j = 0; j < 8; j++) {
      int k = k0 + j;
      float w = W[k * M + col];
      if (KA > 0 && k < KA) w *= scA[k];
      if (KB > 0 && k >= KA && k < KA + KB) w *= scB[k - KA];
      f[j] = w;
    }
    ((uint4*)Wz)[t] = pack8(f);
  } else if (t < KT * MT * 64 + M) {
    int j = t - KT * MT * 64;
    float acc = b[j];
    if (KA > 0)
      for (int k = 0; k < KA; k++) acc += shA[k] * W[k * M + j];
    if (KB > 0)
      for (int k = 0; k < KB; k++) acc += shB[k] * W[(KA + k) * M + j];
    bf[j] = acc;
  }
}

// ============ MFMA GEMM + bias + relu + column stats ============
template <int K1, int K2, int M, bool OUTF32>
__global__ __launch_bounds__(256) void gemm_mfma(
    const unsigned short* __restrict__ A1,
    const unsigned short* __restrict__ A2,
    const unsigned short* __restrict__ Wz, const float* __restrict__ bias,
    void* __restrict__ hOut, double* __restrict__ stats) {
  constexpr int K = K1 + K2;
  constexpr int KT = K / 32;
  constexpr int MT = M / 16;
  constexpr int NT = NN / 16;  // 3125
  int tid = threadIdx.x;
  int wave = tid >> 6, lane = tid & 63;
  int lr = lane & 15, lk = lane >> 4;

  float bj[MT], s[MT], q[MT];
#pragma unroll
  for (int ct = 0; ct < MT; ct++) {
    bj[ct] = bias[ct * 16 + lr];
    s[ct] = 0.f;
    q[ct] = 0.f;
  }

  for (int tt = blockIdx.x * 4 + wave; tt < NT; tt += gridDim.x * 4) {
    float4v acc[MT];
#pragma unroll
    for (int ct = 0; ct < MT; ct++) acc[ct] = (float4v){0.f, 0.f, 0.f, 0.f};

    const unsigned short* a1 = A1 + (size_t)(tt * 16 + lr) * K1 + lk * 8;
    const unsigned short* a2 =
        (K2 > 0) ? A2 + (size_t)(tt * 16 + lr) * K2 + lk * 8 : a1;
#pragma unroll
    for (int kt = 0; kt < KT; kt++) {
      short8v av;
      if (kt * 32 < K1)
        av = *reinterpret_cast<const short8v*>(a1 + kt * 32);
      else
        av = *reinterpret_cast<const short8v*>(a2 + (kt * 32 - K1));
#pragma unroll
      for (int ct = 0; ct < MT; ct++) {
        short8v bv = *reinterpret_cast<const short8v*>(
            Wz + ((size_t)(kt * MT + ct) * 64 + lane) * 8);
        acc[ct] =
            __builtin_amdgcn_mfma_f32_16x16x32_bf16(av, bv, acc[ct], 0, 0, 0);
      }
    }
#pragma unroll
    for (int ct = 0; ct < MT; ct++) {
#pragma unroll
      for (int i = 0; i < 4; i++) {
        float o = fmaxf(acc[ct][i] + bj[ct], 0.f);
        size_t row = (size_t)tt * 16 + lk * 4 + i;
        if (OUTF32)
          ((float*)hOut)[row * M + ct * 16 + lr] = o;
        else
          ((unsigned short*)hOut)[row * M + ct * 16 + lr] = f2bf(o);
        s[ct] += o;
        q[ct] += o * o;
      }
    }
  }

  __shared__ float sred[4][M], qred[4][M];
#pragma unroll
  for (int ct = 0; ct < MT; ct++) {
    float ss = s[ct], qq = q[ct];
    ss += __shfl_xor(ss, 16);
    ss += __shfl_xor(ss, 32);
    qq += __shfl_xor(qq, 16);
    qq += __shfl_xor(qq, 32);
    if (lk == 0) {
      sred[wave][ct * 16 + lr] = ss;
      qred[wave][ct * 16 + lr] = qq;
    }
  }
  __syncthreads();
  if (tid < M) {
    double ss = (double)sred[0][tid] + sred[1][tid] + sred[2][tid] + sred[3][tid];
    double qq = (double)qred[0][tid] + qred[1][tid] + qred[2][tid] + qred[3][tid];
    atomicAdd(&stats[tid], ss);
    atomicAdd(&stats[M + tid], qq);
  }
}

// ============ final: BN coeffs + normalize, M=16, fp32 ============
__global__ __launch_bounds__(256) void bnout(const float4* __restrict__ h,
                                             const double* __restrict__ stats,
                                             const float* __restrict__ g,
                                             const float* __restrict__ beta,
                                             float4* __restrict__ out) {
  __shared__ float sc[16], sh[16];
  int tid = threadIdx.x;
  if (tid < 16) {
    double mu = stats[tid] / (double)NN;
    double var = stats[16 + tid] / (double)NN - mu * mu;
    double inv = 1.0 / sqrt(var + (double)BN_EPS);
    double scale = (double)g[tid] * inv;
    sc[tid] = (float)scale;
    sh[tid] = (float)((double)beta[tid] - mu * scale);
  }
  __syncthreads();
  int t = blockIdx.x * 256 + tid;
  if (t >= NN * 4) return;
  float4 v = h[t];
  int j0 = (4 * t) & 15;
  float4 o;
  o.x = fmaf(v.x, sc[j0 + 0], sh[j0 + 0]);
  o.y = fmaf(v.y, sc[j0 + 1], sh[j0 + 1]);
  o.z = fmaf(v.z, sc[j0 + 2], sh[j0 + 2]);
  o.w = fmaf(v.w, sc[j0 + 3], sh[j0 + 3]);
  out[t] = o;
}

static inline char* alignup(char* p, size_t a) {
  return (char*)(((uintptr_t)p + a - 1) & ~(uintptr_t)(a - 1));
}

extern "C" void kernel_launch(void* const* d_in, const int* in_sizes, int n_in,
                              void* d_out, int out_size, void* d_ws,
                              size_t ws_size, hipStream_t stream) {
  const float* x = (const float*)d_in[0];
  const float* ea = (const float*)d_in[1];
  const int* ei = (const int*)d_in[2];
  const int* src = ei;
  const int* dst = ei + NE;
  const float* lin_w = (const float*)d_in[3];
  const float* lin_b = (const float*)d_in[4];
  const float* c1_w = (const float*)d_in[5];
  const float* c1_b = (const float*)d_in[6];
  const float* c1_g = (const float*)d_in[7];
  const float* c1_be = (const float*)d_in[8];
  const float* c2_w = (const float*)d_in[9];
  const float* c2_b = (const float*)d_in[10];
  const float* c2_g = (const float*)d_in[11];
  const float* c2_be = (const float*)d_in[12];
  const float* l1_w = (const float*)d_in[13];
  const float* l1_b = (const float*)d_in[14];
  const float* l1_g = (const float*)d_in[15];
  const float* l1_be = (const float*)d_in[16];
  const float* ma_w = (const float*)d_in[17];
  const float* ma_b = (const float*)d_in[18];
  const float* ma_g = (const float*)d_in[19];
  const float* ma_be = (const float*)d_in[20];
  const float* mb_w = (const float*)d_in[21];
  const float* mb_b = (const float*)d_in[22];
  const float* mb_g = (const float*)d_in[23];
  const float* mb_be = (const float*)d_in[24];

  typedef unsigned short us;
  char* p = (char*)d_ws;
  us* xb = (us*)p;   p += (size_t)NN * 96 * 2;
  us* Ab = (us*)p;   p += (size_t)NN * 96 * 2;
  us* H1 = (us*)p;   p += (size_t)NN * 96 * 2;
  us* H2 = (us*)p;   p += (size_t)NN * 64 * 2;
  us* H3 = (us*)p;   p += (size_t)NN * 96 * 2;
  us* H4 = (us*)p;   p += (size_t)NN * 96 * 2;
  float* H5 = (float*)p; p += (size_t)NN * 16 * 4;
  p = alignup(p, 256);
  us* Wz1 = (us*)p;  p += 3 * 6 * 64 * 8 * 2;
  us* Wz2 = (us*)p;  p += 3 * 4 * 64 * 8 * 2;
  us* Wz3 = (us*)p;  p += 5 * 6 * 64 * 8 * 2;
  us* Wz4 = (us*)p;  p += 3 * 6 * 64 * 8 * 2;
  us* Wz5 = (us*)p;  p += 3 * 1 * 64 * 8 * 2;
  p = alignup(p, 256);
  float* bf1 = (float*)p; p += 96 * 4;
  float* bf2 = (float*)p; p += 64 * 4;
  float* bf3 = (float*)p; p += 96 * 4;
  float* bf4 = (float*)p; p += 96 * 4;
  float* bf5 = (float*)p; p += 16 * 4;
  p = alignup(p, 256);
  char* zbase = p;
  int* counts = (int*)p;  p += (size_t)NN * 4;
  double* stats = (double*)p; p += (size_t)5 * 192 * 8;
  size_t zbytes = (size_t)(p - zbase);
  int* rowstart = (int*)p; p += (size_t)(NN + 1) * 4;
  int* bsum = (int*)p;    p += 256 * 4;
  int* boff = (int*)p;    p += 256 * 4;
  int* rank = (int*)p;    p += (size_t)NE * 4;
  unsigned* pack = (unsigned*)p; p += (size_t)NE * 4;

  hipMemsetAsync(zbase, 0, zbytes, stream);

  const int eb = (NE + 255) / 256;
  const int n12 = NN * 12;
  const int b12 = (n12 + 255) / 256;
  const int aggG = NN / 4;  // 12500, exact
  const int GG = 782;       // ceil(3125 tiles / 4 waves): 1 tile per wave

  // ---- prep ----
  f2bf_k<<<b12, 256, 0, stream>>>(x, xb, n12);
  hist_rank<<<eb, 256, 0, stream>>>(dst, counts, rank);
  scan_part<<<NB, 256, 0, stream>>>(counts, bsum);
  scan_top<<<1, 256, 0, stream>>>(bsum, boff);
  scan_apply<<<NB, 256, 0, stream>>>(counts, boff, rowstart);
  scatter_k<<<eb, 256, 0, stream>>>(src, dst, ea, rowstart, rank, pack);

  // ---- conv1 ----
  agg_wave<<<aggG, 256, 0, stream>>>(xb, lin_w, lin_b, rowstart, pack, Ab);
  wprep<96, 96, 0, 0><<<5, 256, 0, stream>>>(
      c1_w, c1_b, nullptr, nullptr, nullptr, nullptr, nullptr, nullptr, Wz1,
      bf1);
  gemm_mfma<96, 0, 96, false><<<GG, 256, 0, stream>>>(Ab, nullptr, Wz1, bf1,
                                                      H1, stats);

  // ---- conv2 (BN1 computed from stats, applied on the fly to H1) ----
  agg_wave_norm<<<aggG, 256, 0, stream>>>(H1, stats, c1_g, c1_be, lin_w, lin_b,
                                          rowstart, pack, Ab);
  wprep<96, 64, 0, 0><<<4, 256, 0, stream>>>(
      c2_w, c2_b, nullptr, nullptr, nullptr, nullptr, nullptr, nullptr, Wz2,
      bf2);
  gemm_mfma<96, 0, 64, false><<<GG, 256, 0, stream>>>(Ab, nullptr, Wz2, bf2,
                                                      H2, stats + 192);

  // ---- lin1 on concat([H1(BN1 folded), H2(BN2 folded)]) ----
  wprep<160, 96, 96, 64><<<8, 256, 0, stream>>>(l1_w, l1_b, stats, c1_g, c1_be,
                                                stats + 192, c2_g, c2_be, Wz3,
                                                bf3);
  gemm_mfma<96, 64, 96, false><<<GG, 256, 0, stream>>>(H1, H2, Wz3, bf3, H3,
                                                       stats + 384);

  // ---- mlp1a (BN3 folded) ----
  wprep<96, 96, 96, 0><<<5, 256, 0, stream>>>(ma_w, ma_b, stats + 384, l1_g,
                                              l1_be, nullptr, nullptr, nullptr,
                                              Wz4, bf4);
  gemm_mfma<96, 0, 96, false><<<GG, 256, 0, stream>>>(H3, nullptr, Wz4, bf4,
                                                      H4, stats + 576);

  // ---- mlp1b (BN4 folded) -> H5 fp32, then fused BN5+write ----
  wprep<96, 16, 96, 0><<<1, 256, 0, stream>>>(mb_w, mb_b, stats + 576, ma_g,
                                              ma_be, nullptr, nullptr, nullptr,
                                              Wz5, bf5);
  gemm_mfma<96, 0, 16, true><<<GG, 256, 0, stream>>>(H4, nullptr, Wz5, bf5, H5,
                                                     stats + 768);
  bnout<<<(NN * 4 + 255) / 256, 256, 0, stream>>>(
      (const float4*)H5, stats + 768, mb_g, mb_be, (float4*)d_out);
}